// Round 1
// baseline (1243.372 us; speedup 1.0000x reference)
//
#include <hip/hip_runtime.h>

#define N_NODES 12288
#define IN_DIM_ 256
#define HID_ 64
#define E_EDGES 393216
#define TOT_EDGES (E_EDGES + N_NODES)  // 405504

// ---------------------------------------------------------------- graph build

__global__ __launch_bounds__(256) void k_init(const float* __restrict__ x,
                                              int* __restrict__ deg,
                                              float* __restrict__ coef) {
  int i = blockIdx.x * 256 + threadIdx.x;
  if (i < N_NODES) {
    deg[i] = 1;  // self loop
    coef[i] = 1.0f - 2.0f * x[(size_t)i * IN_DIM_];
  }
}

__global__ __launch_bounds__(256) void k_count(const int* __restrict__ dst,
                                               int* __restrict__ deg) {
  int e = blockIdx.x * 256 + threadIdx.x;
  if (e < E_EDGES) atomicAdd(&deg[dst[e]], 1);
}

__global__ __launch_bounds__(256) void k_dinv(const int* __restrict__ deg,
                                              float* __restrict__ dinv) {
  int i = blockIdx.x * 256 + threadIdx.x;
  if (i < N_NODES) dinv[i] = 1.0f / sqrtf((float)deg[i]);
}

__global__ __launch_bounds__(1024) void k_scan(const int* __restrict__ deg,
                                               int* __restrict__ rowptr,
                                               int* __restrict__ cursor) {
  __shared__ int sh[1024];
  const int t = threadIdx.x;
  int loc[12];
  int s = 0;
#pragma unroll
  for (int i = 0; i < 12; i++) { loc[i] = s; s += deg[t * 12 + i]; }
  sh[t] = s;
  __syncthreads();
  for (int off = 1; off < 1024; off <<= 1) {
    int v = (t >= off) ? sh[t - off] : 0;
    __syncthreads();
    sh[t] += v;
    __syncthreads();
  }
  int base = sh[t] - s;  // exclusive
#pragma unroll
  for (int i = 0; i < 12; i++) {
    int v = base + loc[i];
    rowptr[t * 12 + i] = v;
    cursor[t * 12 + i] = v;
  }
  if (t == 1023) rowptr[N_NODES] = sh[1023];
}

__global__ __launch_bounds__(256) void k_fill(const int* __restrict__ src,
                                              const int* __restrict__ dst,
                                              const float* __restrict__ dinv,
                                              int* __restrict__ cursor,
                                              int* __restrict__ col,
                                              float* __restrict__ wgt) {
  int e = blockIdx.x * 256 + threadIdx.x;
  if (e < E_EDGES) {
    int s = src[e], d = dst[e];
    int pos = atomicAdd(&cursor[d], 1);
    col[pos] = s;
    wgt[pos] = dinv[s] * dinv[d];
  } else if (e < TOT_EDGES) {
    int i = e - E_EDGES;
    int pos = atomicAdd(&cursor[i], 1);
    col[pos] = i;
    float di = dinv[i];
    wgt[pos] = di * di;
  }
}

// ---------------------------------------------------------------- aggregation
// out[node][f] = sum_e wgt_e * in[col_e][f]   (+bias, relu, rank1 options)

template <bool BIAS, bool RELU, bool RANK1>
__global__ __launch_bounds__(256) void k_agg64(const float* __restrict__ in,
                                               const int* __restrict__ rowptr,
                                               const int* __restrict__ col,
                                               const float* __restrict__ wgt,
                                               const float* __restrict__ bias,
                                               const float* __restrict__ coef,
                                               const float* __restrict__ wrow,
                                               float* __restrict__ out) {
  const int lane = threadIdx.x & 63;
  int node = blockIdx.x * 4 + (threadIdx.x >> 6);
  node = __builtin_amdgcn_readfirstlane(node);
  const int start = rowptr[node];
  const int end = rowptr[node + 1];
  const float wr = RANK1 ? wrow[lane] : 0.0f;
  float acc = 0.0f;
  for (int e = start; e < end; ++e) {
    int c = col[e];
    float wt = wgt[e];
    float v = in[(size_t)c * 64 + lane];
    if (RANK1) v = fmaf(coef[c], wr, v);
    acc = fmaf(wt, v, acc);
  }
  if (BIAS) acc += bias[lane];
  if (RELU) acc = fmaxf(acc, 0.0f);
  out[(size_t)node * 64 + lane] = acc;
}

template <bool BIAS, int LDIN>
__global__ __launch_bounds__(256) void k_agg32(const float* __restrict__ in,
                                               const int* __restrict__ rowptr,
                                               const int* __restrict__ col,
                                               const float* __restrict__ wgt,
                                               const float* __restrict__ bias,
                                               float* __restrict__ out) {
  const int lane = threadIdx.x & 31;
  const int node = blockIdx.x * 8 + (threadIdx.x >> 5);
  const int start = rowptr[node];
  const int end = rowptr[node + 1];
  float acc = 0.0f;
  for (int e = start; e < end; ++e) {
    int c = col[e];
    float wt = wgt[e];
    acc = fmaf(wt, in[(size_t)c * LDIN + lane], acc);
  }
  if (BIAS) acc += bias[lane];
  out[(size_t)node * 32 + lane] = acc;
}

// ---------------------------------------------------------------- small GEMM
// C[M x NF] = A[M x K] @ W[K x NF] (W has leading dim LDW), fp32, W in LDS.

template <int K, int NF, int LDW, int RPT, bool BIAS, bool RELU>
__global__ __launch_bounds__(256) void k_gemm(const float* __restrict__ A,
                                              const float* __restrict__ W,
                                              const float* __restrict__ bias,
                                              float* __restrict__ C) {
  __shared__ float Ws[K * NF];
  for (int i = threadIdx.x; i < K * NF; i += 256) {
    int k = i / NF, c2 = i % NF;
    Ws[i] = W[k * LDW + c2];
  }
  __syncthreads();
  constexpr int G = 256 / NF;
  const int c = threadIdx.x % NF;
  const int rg = threadIdx.x / NF;
  const int r0 = blockIdx.x * (G * RPT) + rg * RPT;
  float acc[RPT];
#pragma unroll
  for (int i = 0; i < RPT; i++) acc[i] = 0.0f;
#pragma unroll 4
  for (int k = 0; k < K; ++k) {
    float wv = Ws[k * NF + c];
#pragma unroll
    for (int i = 0; i < RPT; i++)
      acc[i] = fmaf(A[(size_t)(r0 + i) * K + k], wv, acc[i]);
  }
  float b = BIAS ? bias[c] : 0.0f;
#pragma unroll
  for (int i = 0; i < RPT; i++) {
    float v = acc[i] + b;
    if (RELU) v = fmaxf(v, 0.0f);
    C[(size_t)(r0 + i) * NF + c] = v;
  }
}

// ---------------------------------------------------------------- split z

__global__ __launch_bounds__(256) void k_split(const float* __restrict__ z,
                                               float* __restrict__ zs,
                                               float* __restrict__ zns) {
  int i = blockIdx.x * 256 + threadIdx.x;  // over 12288*16 float4s
  const float4* z4 = (const float4*)z;
  int r = i >> 4, q = i & 15;
  float4 v = z4[i];
  if (q < 8)
    ((float4*)zs)[r * 8 + q] = v;
  else
    ((float4*)zns)[r * 8 + (q - 8)] = v;
}

// ---------------------------------------------------------------- s_ = hs@hs^T
// Tile 128 rows x 64 cols per block, 8x4 micro-tile, K=64 entirely in LDS.

__global__ __launch_bounds__(256) void k_syrk(const float* __restrict__ hs,
                                              float* __restrict__ out) {
  __shared__ float As[64 * 128];  // [k][r]
  __shared__ float Bs[64 * 64];   // [k][c]
  const int tid = threadIdx.x;
  const long rb = (long)blockIdx.y * 128;
  const long cb = (long)blockIdx.x * 64;
  {
    const int r = tid & 127;
    const int half = tid >> 7;  // 0..1
    const float4* g = (const float4*)(hs + (rb + r) * 64);
#pragma unroll
    for (int i = 0; i < 8; i++) {
      const int kq = half * 8 + i;  // float4 index along k: 0..15
      float4 v = g[kq];
      As[(4 * kq + 0) * 128 + r] = v.x;
      As[(4 * kq + 1) * 128 + r] = v.y;
      As[(4 * kq + 2) * 128 + r] = v.z;
      As[(4 * kq + 3) * 128 + r] = v.w;
    }
    const int c = tid & 63;
    const int iq = tid >> 6;  // 0..3
    const float4* gb = (const float4*)(hs + (cb + c) * 64);
#pragma unroll
    for (int j = 0; j < 4; j++) {
      const int kq = iq + 4 * j;  // 0..15
      float4 v = gb[kq];
      Bs[(4 * kq + 0) * 64 + c] = v.x;
      Bs[(4 * kq + 1) * 64 + c] = v.y;
      Bs[(4 * kq + 2) * 64 + c] = v.z;
      Bs[(4 * kq + 3) * 64 + c] = v.w;
    }
  }
  __syncthreads();
  const int tx = tid & 15;
  const int ty = tid >> 4;
  float acc[8][4];
#pragma unroll
  for (int i = 0; i < 8; i++)
#pragma unroll
    for (int j = 0; j < 4; j++) acc[i][j] = 0.0f;
#pragma unroll 4
  for (int k = 0; k < 64; ++k) {
    float4 b = *(const float4*)&Bs[k * 64 + tx * 4];
    float4 a0 = *(const float4*)&As[k * 128 + ty * 8];
    float4 a1 = *(const float4*)&As[k * 128 + ty * 8 + 4];
    float a[8] = {a0.x, a0.y, a0.z, a0.w, a1.x, a1.y, a1.z, a1.w};
    float bb[4] = {b.x, b.y, b.z, b.w};
#pragma unroll
    for (int i = 0; i < 8; i++)
#pragma unroll
      for (int j = 0; j < 4; j++) acc[i][j] = fmaf(a[i], bb[j], acc[i][j]);
  }
#pragma unroll
  for (int i = 0; i < 8; i++) {
    float4 v = {acc[i][0], acc[i][1], acc[i][2], acc[i][3]};
    *(float4*)&out[(rb + ty * 8 + i) * 12288L + cb + tx * 4] = v;
  }
}

// ---------------------------------------------------------------- launch

extern "C" void kernel_launch(void* const* d_in, const int* in_sizes, int n_in,
                              void* d_out, int out_size, void* d_ws,
                              size_t ws_size, hipStream_t stream) {
  (void)in_sizes; (void)n_in; (void)out_size; (void)ws_size;
  const float* x = (const float*)d_in[0];
  const int* ei = (const int*)d_in[1];
  const int* src = ei;
  const int* dst = ei + E_EDGES;
  const float* eW1 = (const float*)d_in[2];
  const float* eb1 = (const float*)d_in[3];
  const float* eW2 = (const float*)d_in[4];
  const float* eb2 = (const float*)d_in[5];
  const float* d1W1 = (const float*)d_in[6];
  const float* d1b1 = (const float*)d_in[7];
  const float* d1W2 = (const float*)d_in[8];
  const float* d1b2 = (const float*)d_in[9];
  const float* d2W1 = (const float*)d_in[10];
  const float* d2b1 = (const float*)d_in[11];
  const float* d2W2 = (const float*)d_in[12];
  const float* d2b2 = (const float*)d_in[13];
  const float* sW = (const float*)d_in[14];
  const float* sb = (const float*)d_in[15];

  float* out = (float*)d_out;
  float* out_zs = out;                  // 12288 x 32
  float* out_zns = out + 393216;        // 12288 x 32
  float* out_xs = out + 786432;         // 12288 x 256
  float* out_xns = out + 3932160;       // 12288 x 256
  float* out_xscf = out + 7077888;      // 12288 x 256
  float* out_s = out + 10223616;        // 12288 x 12288

  char* w = (char*)d_ws;
  size_t o = 0;
  auto alloc = [&](size_t bytes) -> void* {
    void* p = (void*)(w + o);
    o += (bytes + 255) & ~(size_t)255;
    return p;
  };
  int* deg = (int*)alloc(N_NODES * 4);
  int* rowptr = (int*)alloc((N_NODES + 1) * 4);
  int* cursor = (int*)alloc(N_NODES * 4);
  int* col = (int*)alloc(TOT_EDGES * 4);
  float* wgt = (float*)alloc(TOT_EDGES * 4);
  float* dinv = (float*)alloc(N_NODES * 4);
  float* coef = (float*)alloc(N_NODES * 4);
  const size_t B64 = (size_t)N_NODES * 64 * 4;
  const size_t B32 = (size_t)N_NODES * 32 * 4;
  float* slotA = (float*)alloc(B64);  // HWe1 / HWe2 / hs
  float* slotB = (float*)alloc(B64);  // h1 / u1 / u1cf / u2
  float* slotC = (float*)alloc(B64);  // h1cf / g2 / g2cf / g2ns
  float* z = (float*)alloc(B64);
  float* slotD = (float*)alloc(B32);  // t32 / gs / gscf
  float* slotE = (float*)alloc(B32);  // zscf / gns

  // ---- graph build
  k_init<<<48, 256, 0, stream>>>(x, deg, coef);
  k_count<<<1536, 256, 0, stream>>>(dst, deg);
  k_dinv<<<48, 256, 0, stream>>>(deg, dinv);
  k_scan<<<1, 1024, 0, stream>>>(deg, rowptr, cursor);
  k_fill<<<1584, 256, 0, stream>>>(src, dst, dinv, cursor, col, wgt);

  // ---- encoder
  // HWe1 = x @ enc_W1
  k_gemm<256, 64, 64, 8, false, false><<<384, 256, 0, stream>>>(x, eW1, nullptr, slotA);
  // h1 = relu(A(HWe1) + b1)
  k_agg64<true, true, false><<<3072, 256, 0, stream>>>(slotA, rowptr, col, wgt, eb1, nullptr, nullptr, slotB);
  // h1cf = relu(A(HWe1 + coef⊗W1row0) + b1)     (rank-1 fused)
  k_agg64<true, true, true><<<3072, 256, 0, stream>>>(slotA, rowptr, col, wgt, eb1, coef, eW1, slotC);
  // HWe2 = h1 @ enc_W2   (reuse slotA)
  k_gemm<64, 64, 64, 8, false, false><<<384, 256, 0, stream>>>(slotB, eW2, nullptr, slotA);
  // z = A(HWe2) + b2
  k_agg64<true, false, false><<<3072, 256, 0, stream>>>(slotA, rowptr, col, wgt, eb2, nullptr, nullptr, z);
  // t32 = h1cf @ enc_W2[:, :32]
  k_gemm<64, 32, 64, 4, false, false><<<384, 256, 0, stream>>>(slotC, eW2, nullptr, slotD);
  // zscf = A(t32) + b2[:32]
  k_agg32<true, 32><<<1536, 256, 0, stream>>>(slotD, rowptr, col, wgt, eb2, slotE);
  // write z_s, z_ns outputs
  k_split<<<768, 256, 0, stream>>>(z, out_zs, out_zns);

  // ---- dec1(z_s)
  k_agg32<false, 64><<<1536, 256, 0, stream>>>(z, rowptr, col, wgt, nullptr, slotD);       // gs = A(z_s)
  k_gemm<32, 64, 64, 8, true, true><<<384, 256, 0, stream>>>(slotD, d1W1, d1b1, slotB);    // u1
  k_agg64<false, false, false><<<3072, 256, 0, stream>>>(slotB, rowptr, col, wgt, nullptr, nullptr, nullptr, slotC);  // g2
  k_gemm<64, 256, 256, 8, true, false><<<1536, 256, 0, stream>>>(slotC, d1W2, d1b2, out_xs);

  // ---- dec1(z_s_cf)
  k_agg32<false, 32><<<1536, 256, 0, stream>>>(slotE, rowptr, col, wgt, nullptr, slotD);   // gscf = A(zscf)
  k_gemm<32, 64, 64, 8, true, true><<<384, 256, 0, stream>>>(slotD, d1W1, d1b1, slotB);    // u1cf
  k_agg64<false, false, false><<<3072, 256, 0, stream>>>(slotB, rowptr, col, wgt, nullptr, nullptr, nullptr, slotC);
  k_gemm<64, 256, 256, 8, true, false><<<1536, 256, 0, stream>>>(slotC, d1W2, d1b2, out_xscf);

  // ---- gns = A(z_ns), shared by dec2 and s-conv  (reuse slotE; zscf dead)
  k_agg32<false, 64><<<1536, 256, 0, stream>>>(z + 32, rowptr, col, wgt, nullptr, slotE);

  // ---- dec2(z_ns)
  k_gemm<32, 64, 64, 8, true, true><<<384, 256, 0, stream>>>(slotE, d2W1, d2b1, slotB);    // u2
  k_agg64<false, false, false><<<3072, 256, 0, stream>>>(slotB, rowptr, col, wgt, nullptr, nullptr, nullptr, slotC);
  k_gemm<64, 256, 256, 8, true, false><<<1536, 256, 0, stream>>>(slotC, d2W2, d2b2, out_xns);

  // ---- hs = gns @ s_W + s_b  (reuse slotA)
  k_gemm<32, 64, 64, 8, true, false><<<384, 256, 0, stream>>>(slotE, sW, sb, slotA);

  // ---- s_ = hs @ hs^T
  k_syrk<<<dim3(192, 96), 256, 0, stream>>>(slotA, out_s);
}

// Round 2
// 1076.083 us; speedup vs baseline: 1.1555x; 1.1555x over previous
//
#include <hip/hip_runtime.h>

#define N_NODES 12288
#define IN_DIM_ 256
#define HID_ 64
#define E_EDGES 393216
#define TOT_EDGES (E_EDGES + N_NODES)  // 405504

typedef __attribute__((ext_vector_type(8))) short bf16x8;
typedef __attribute__((ext_vector_type(16))) float f32x16;

__device__ inline unsigned short f2bf_rne(float f) {
  unsigned int u = __float_as_uint(f);
  unsigned int r = u + 0x7fffu + ((u >> 16) & 1u);
  return (unsigned short)(r >> 16);
}
__device__ inline float bf2f(unsigned short h) {
  return __uint_as_float(((unsigned int)h) << 16);
}

// ---------------------------------------------------------------- graph build

__global__ __launch_bounds__(256) void k_init(const float* __restrict__ x,
                                              int* __restrict__ deg,
                                              float* __restrict__ coef) {
  int i = blockIdx.x * 256 + threadIdx.x;
  if (i < N_NODES) {
    deg[i] = 1;  // self loop
    coef[i] = 1.0f - 2.0f * x[(size_t)i * IN_DIM_];
  }
}

__global__ __launch_bounds__(256) void k_count(const int* __restrict__ dst,
                                               int* __restrict__ deg) {
  int e = blockIdx.x * 256 + threadIdx.x;
  if (e < E_EDGES) atomicAdd(&deg[dst[e]], 1);
}

// scan over degrees -> rowptr/cursor, plus dinv = rsqrt(deg)
__global__ __launch_bounds__(1024) void k_scan(const int* __restrict__ deg,
                                               int* __restrict__ rowptr,
                                               int* __restrict__ cursor,
                                               float* __restrict__ dinv) {
  __shared__ int sh[1024];
  const int t = threadIdx.x;
  int loc[12];
  int s = 0;
#pragma unroll
  for (int i = 0; i < 12; i++) {
    int d = deg[t * 12 + i];
    dinv[t * 12 + i] = 1.0f / sqrtf((float)d);
    loc[i] = s;
    s += d;
  }
  sh[t] = s;
  __syncthreads();
  for (int off = 1; off < 1024; off <<= 1) {
    int v = (t >= off) ? sh[t - off] : 0;
    __syncthreads();
    sh[t] += v;
    __syncthreads();
  }
  int base = sh[t] - s;  // exclusive
#pragma unroll
  for (int i = 0; i < 12; i++) {
    int v = base + loc[i];
    rowptr[t * 12 + i] = v;
    cursor[t * 12 + i] = v;
  }
  if (t == 1023) rowptr[N_NODES] = sh[1023];
}

__global__ __launch_bounds__(256) void k_fill(const int* __restrict__ src,
                                              const int* __restrict__ dst,
                                              const float* __restrict__ dinv,
                                              int* __restrict__ cursor,
                                              int* __restrict__ col,
                                              float* __restrict__ wgt) {
  int e = blockIdx.x * 256 + threadIdx.x;
  if (e < E_EDGES) {
    int s = src[e], d = dst[e];
    int pos = atomicAdd(&cursor[d], 1);
    col[pos] = s;
    wgt[pos] = dinv[s] * dinv[d];
  } else if (e < TOT_EDGES) {
    int i = e - E_EDGES;
    int pos = atomicAdd(&cursor[i], 1);
    col[pos] = i;
    float di = dinv[i];
    wgt[pos] = di * di;
  }
}

// ---------------------------------------------------------------- aggregation
// out[node][f] = sum_e wgt_e * in[col_e][f]. One wave per node, unroll-4 for
// memory-level parallelism (4 independent gathers in flight).

template <bool BIAS, bool RELU, bool RANK1, bool SPLIT>
__global__ __launch_bounds__(256) void k_agg64(const float* __restrict__ in,
                                               const int* __restrict__ rowptr,
                                               const int* __restrict__ col,
                                               const float* __restrict__ wgt,
                                               const float* __restrict__ bias,
                                               const float* __restrict__ coef,
                                               const float* __restrict__ wrow,
                                               float* __restrict__ out,
                                               float* __restrict__ out2) {
  const int lane = threadIdx.x & 63;
  int node = blockIdx.x * 4 + (threadIdx.x >> 6);
  node = __builtin_amdgcn_readfirstlane(node);
  const int start = rowptr[node];
  const int end = rowptr[node + 1];
  const float wr = RANK1 ? wrow[lane] : 0.0f;
  float a0 = 0.0f, a1 = 0.0f, a2 = 0.0f, a3 = 0.0f;
  int e = start;
  for (; e + 4 <= end; e += 4) {
    int c0 = col[e + 0], c1 = col[e + 1], c2 = col[e + 2], c3 = col[e + 3];
    float w0 = wgt[e + 0], w1 = wgt[e + 1], w2 = wgt[e + 2], w3 = wgt[e + 3];
    float v0 = in[(size_t)c0 * 64 + lane];
    float v1 = in[(size_t)c1 * 64 + lane];
    float v2 = in[(size_t)c2 * 64 + lane];
    float v3 = in[(size_t)c3 * 64 + lane];
    if (RANK1) {
      v0 = fmaf(coef[c0], wr, v0);
      v1 = fmaf(coef[c1], wr, v1);
      v2 = fmaf(coef[c2], wr, v2);
      v3 = fmaf(coef[c3], wr, v3);
    }
    a0 = fmaf(w0, v0, a0);
    a1 = fmaf(w1, v1, a1);
    a2 = fmaf(w2, v2, a2);
    a3 = fmaf(w3, v3, a3);
  }
  for (; e < end; ++e) {
    int c = col[e];
    float v = in[(size_t)c * 64 + lane];
    if (RANK1) v = fmaf(coef[c], wr, v);
    a0 = fmaf(wgt[e], v, a0);
  }
  float acc = (a0 + a1) + (a2 + a3);
  if (BIAS) acc += bias[lane];
  if (RELU) acc = fmaxf(acc, 0.0f);
  if (SPLIT) {
    if (lane < 32)
      out[(size_t)node * 32 + lane] = acc;
    else
      out2[(size_t)node * 32 + (lane - 32)] = acc;
  } else {
    out[(size_t)node * 64 + lane] = acc;
  }
}

template <bool BIAS>
__global__ __launch_bounds__(256) void k_agg32(const float* __restrict__ in,
                                               const int* __restrict__ rowptr,
                                               const int* __restrict__ col,
                                               const float* __restrict__ wgt,
                                               const float* __restrict__ bias,
                                               float* __restrict__ out) {
  const int lane = threadIdx.x & 31;
  const int node = blockIdx.x * 8 + (threadIdx.x >> 5);
  const int start = rowptr[node];
  const int end = rowptr[node + 1];
  float a0 = 0.0f, a1 = 0.0f, a2 = 0.0f, a3 = 0.0f;
  int e = start;
  for (; e + 4 <= end; e += 4) {
    int c0 = col[e + 0], c1 = col[e + 1], c2 = col[e + 2], c3 = col[e + 3];
    float w0 = wgt[e + 0], w1 = wgt[e + 1], w2 = wgt[e + 2], w3 = wgt[e + 3];
    a0 = fmaf(w0, in[(size_t)c0 * 32 + lane], a0);
    a1 = fmaf(w1, in[(size_t)c1 * 32 + lane], a1);
    a2 = fmaf(w2, in[(size_t)c2 * 32 + lane], a2);
    a3 = fmaf(w3, in[(size_t)c3 * 32 + lane], a3);
  }
  for (; e < end; ++e) a0 = fmaf(wgt[e], in[(size_t)col[e] * 32 + lane], a0);
  float acc = (a0 + a1) + (a2 + a3);
  if (BIAS) acc += bias[lane];
  out[(size_t)node * 32 + lane] = acc;
}

// ---------------------------------------------------------------- small GEMM
// C[M x NF] = A[M x K] @ W[K x NF] (leading dim LDW), fp32, W in LDS.

template <int K, int NF, int LDW, int RPT, bool BIAS, bool RELU>
__global__ __launch_bounds__(256) void k_gemm(const float* __restrict__ A,
                                              const float* __restrict__ W,
                                              const float* __restrict__ bias,
                                              float* __restrict__ C) {
  __shared__ float Ws[K * NF];
  for (int i = threadIdx.x; i < K * NF; i += 256) {
    int k = i / NF, c2 = i % NF;
    Ws[i] = W[k * LDW + c2];
  }
  __syncthreads();
  constexpr int G = 256 / NF;
  const int c = threadIdx.x % NF;
  const int rg = threadIdx.x / NF;
  const int r0 = blockIdx.x * (G * RPT) + rg * RPT;
  float acc[RPT];
#pragma unroll
  for (int i = 0; i < RPT; i++) acc[i] = 0.0f;
#pragma unroll 4
  for (int k = 0; k < K; ++k) {
    float wv = Ws[k * NF + c];
#pragma unroll
    for (int i = 0; i < RPT; i++)
      acc[i] = fmaf(A[(size_t)(r0 + i) * K + k], wv, acc[i]);
  }
  float b = BIAS ? bias[c] : 0.0f;
#pragma unroll
  for (int i = 0; i < RPT; i++) {
    float v = acc[i] + b;
    if (RELU) v = fmaxf(v, 0.0f);
    C[(size_t)(r0 + i) * NF + c] = v;
  }
}

// hs = gns @ s_W + s_b, written directly as bf16 hi/lo split (for MFMA syrk)
__global__ __launch_bounds__(256) void k_gemm_hs(const float* __restrict__ A,
                                                 const float* __restrict__ W,
                                                 const float* __restrict__ bias,
                                                 unsigned short* __restrict__ hi,
                                                 unsigned short* __restrict__ lo) {
  __shared__ float Ws[32 * 64];
  for (int i = threadIdx.x; i < 32 * 64; i += 256) {
    int k = i / 64, c2 = i % 64;
    Ws[i] = W[k * 64 + c2];
  }
  __syncthreads();
  const int c = threadIdx.x % 64;
  const int rg = threadIdx.x / 64;
  const int r0 = blockIdx.x * 32 + rg * 8;
  float acc[8];
#pragma unroll
  for (int i = 0; i < 8; i++) acc[i] = 0.0f;
#pragma unroll 4
  for (int k = 0; k < 32; ++k) {
    float wv = Ws[k * 64 + c];
#pragma unroll
    for (int i = 0; i < 8; i++)
      acc[i] = fmaf(A[(size_t)(r0 + i) * 32 + k], wv, acc[i]);
  }
  float b = bias[c];
#pragma unroll
  for (int i = 0; i < 8; i++) {
    float v = acc[i] + b;
    unsigned short h = f2bf_rne(v);
    float l = v - bf2f(h);
    hi[(size_t)(r0 + i) * 64 + c] = h;
    lo[(size_t)(r0 + i) * 64 + c] = f2bf_rne(l);
  }
}

// ---------------------------------------------------------------- s_ = hs@hs^T
// bf16 MFMA (32x32x16), hi/lo split: hi*hi + hi*lo + lo*hi ~ fp32 accuracy.
// Block = 256 threads = 4 waves (2x2); wave computes 2x2 tiles of 32x32.
// Block tile 128x128. Operands are L2-resident (3 MB) -> load global direct.

__global__ __launch_bounds__(256) void k_syrk_mfma(
    const unsigned short* __restrict__ hhi, const unsigned short* __restrict__ hlo,
    float* __restrict__ out) {
  const int tid = threadIdx.x;
  const int lane = tid & 63;
  const int wave = tid >> 6;
  const int wy = wave >> 1, wx = wave & 1;
  const int m = lane & 31;
  const int koff = (lane >> 5) * 8;
  const size_t rb = (size_t)blockIdx.y * 128 + wy * 64;
  const size_t cb = (size_t)blockIdx.x * 128 + wx * 64;
  f32x16 acc[2][2];
#pragma unroll
  for (int i = 0; i < 2; i++)
#pragma unroll
    for (int j = 0; j < 2; j++) acc[i][j] = (f32x16)(0.0f);
#pragma unroll
  for (int k0 = 0; k0 < 64; k0 += 16) {
    bf16x8 ah[2], al[2], bh[2], bl[2];
#pragma unroll
    for (int t = 0; t < 2; t++) {
      size_t ra = (rb + t * 32 + m) * 64 + k0 + koff;
      ah[t] = *(const bf16x8*)(hhi + ra);
      al[t] = *(const bf16x8*)(hlo + ra);
      size_t rc = (cb + t * 32 + m) * 64 + k0 + koff;
      bh[t] = *(const bf16x8*)(hhi + rc);
      bl[t] = *(const bf16x8*)(hlo + rc);
    }
#pragma unroll
    for (int i = 0; i < 2; i++)
#pragma unroll
      for (int j = 0; j < 2; j++) {
        acc[i][j] = __builtin_amdgcn_mfma_f32_32x32x16_bf16(ah[i], bh[j], acc[i][j], 0, 0, 0);
        acc[i][j] = __builtin_amdgcn_mfma_f32_32x32x16_bf16(ah[i], bl[j], acc[i][j], 0, 0, 0);
        acc[i][j] = __builtin_amdgcn_mfma_f32_32x32x16_bf16(al[i], bh[j], acc[i][j], 0, 0, 0);
      }
  }
  // C/D layout (32x32): col = lane&31, row = (r&3) + 8*(r>>2) + 4*(lane>>5)
  const int rowoff = 4 * (lane >> 5);
  const int colc = lane & 31;
#pragma unroll
  for (int i = 0; i < 2; i++)
#pragma unroll
    for (int j = 0; j < 2; j++)
#pragma unroll
      for (int r = 0; r < 16; r++) {
        size_t row = rb + i * 32 + (r & 3) + 8 * (r >> 2) + rowoff;
        out[row * 12288 + cb + j * 32 + colc] = acc[i][j][r];
      }
}

// ---------------------------------------------------------------- launch

extern "C" void kernel_launch(void* const* d_in, const int* in_sizes, int n_in,
                              void* d_out, int out_size, void* d_ws,
                              size_t ws_size, hipStream_t stream) {
  (void)in_sizes; (void)n_in; (void)out_size; (void)ws_size;
  const float* x = (const float*)d_in[0];
  const int* ei = (const int*)d_in[1];
  const int* src = ei;
  const int* dst = ei + E_EDGES;
  const float* eW1 = (const float*)d_in[2];
  const float* eb1 = (const float*)d_in[3];
  const float* eW2 = (const float*)d_in[4];
  const float* eb2 = (const float*)d_in[5];
  const float* d1W1 = (const float*)d_in[6];
  const float* d1b1 = (const float*)d_in[7];
  const float* d1W2 = (const float*)d_in[8];
  const float* d1b2 = (const float*)d_in[9];
  const float* d2W1 = (const float*)d_in[10];
  const float* d2b1 = (const float*)d_in[11];
  const float* d2W2 = (const float*)d_in[12];
  const float* d2b2 = (const float*)d_in[13];
  const float* sW = (const float*)d_in[14];
  const float* sb = (const float*)d_in[15];

  float* out = (float*)d_out;
  float* out_zs = out;                  // 12288 x 32
  float* out_zns = out + 393216;        // 12288 x 32
  float* out_xs = out + 786432;         // 12288 x 256
  float* out_xns = out + 3932160;       // 12288 x 256
  float* out_xscf = out + 7077888;      // 12288 x 256
  float* out_s = out + 10223616;        // 12288 x 12288

  char* w = (char*)d_ws;
  size_t o = 0;
  auto alloc = [&](size_t bytes) -> void* {
    void* p = (void*)(w + o);
    o += (bytes + 255) & ~(size_t)255;
    return p;
  };
  int* deg = (int*)alloc(N_NODES * 4);
  int* rowptr = (int*)alloc((N_NODES + 1) * 4);
  int* cursor = (int*)alloc(N_NODES * 4);
  int* col = (int*)alloc(TOT_EDGES * 4);
  float* wgt = (float*)alloc(TOT_EDGES * 4);
  float* dinv = (float*)alloc(N_NODES * 4);
  float* coef = (float*)alloc(N_NODES * 4);
  const size_t B64 = (size_t)N_NODES * 64 * 4;
  const size_t B32 = (size_t)N_NODES * 32 * 4;
  float* slotA = (float*)alloc(B64);  // HWe1 / HWe2
  float* slotB = (float*)alloc(B64);  // h1 / u1 / u1cf / u2
  float* slotC = (float*)alloc(B64);  // h1cf / g2 / g2cf / g2ns
  float* slotD = (float*)alloc(B32);  // t32 / gs / gscf
  float* slotE = (float*)alloc(B32);  // zscf / gns
  unsigned short* hhi = (unsigned short*)alloc((size_t)N_NODES * 64 * 2);
  unsigned short* hlo = (unsigned short*)alloc((size_t)N_NODES * 64 * 2);

  // ---- graph build
  k_init<<<48, 256, 0, stream>>>(x, deg, coef);
  k_count<<<1536, 256, 0, stream>>>(dst, deg);
  k_scan<<<1, 1024, 0, stream>>>(deg, rowptr, cursor, dinv);
  k_fill<<<1584, 256, 0, stream>>>(src, dst, dinv, cursor, col, wgt);

  // ---- encoder
  k_gemm<256, 64, 64, 8, false, false><<<384, 256, 0, stream>>>(x, eW1, nullptr, slotA);
  // h1 = relu(A(HWe1) + b1)
  k_agg64<true, true, false, false><<<3072, 256, 0, stream>>>(slotA, rowptr, col, wgt, eb1, nullptr, nullptr, slotB, nullptr);
  // h1cf = relu(A(HWe1 + coef⊗W1row0) + b1)   (rank-1 fused)
  k_agg64<true, true, true, false><<<3072, 256, 0, stream>>>(slotA, rowptr, col, wgt, eb1, coef, eW1, slotC, nullptr);
  // HWe2 = h1 @ enc_W2
  k_gemm<64, 64, 64, 8, false, false><<<384, 256, 0, stream>>>(slotB, eW2, nullptr, slotA);
  // z = A(HWe2) + b2, split-written straight into out_zs / out_zns
  k_agg64<true, false, false, true><<<3072, 256, 0, stream>>>(slotA, rowptr, col, wgt, eb2, nullptr, nullptr, out_zs, out_zns);
  // t32 = h1cf @ enc_W2[:, :32]
  k_gemm<64, 32, 64, 4, false, false><<<384, 256, 0, stream>>>(slotC, eW2, nullptr, slotD);
  // zscf = A(t32) + b2[:32]
  k_agg32<true><<<1536, 256, 0, stream>>>(slotD, rowptr, col, wgt, eb2, slotE);

  // ---- dec1(z_s)
  k_agg32<false><<<1536, 256, 0, stream>>>(out_zs, rowptr, col, wgt, nullptr, slotD);      // gs
  k_gemm<32, 64, 64, 8, true, true><<<384, 256, 0, stream>>>(slotD, d1W1, d1b1, slotB);    // u1
  k_agg64<false, false, false, false><<<3072, 256, 0, stream>>>(slotB, rowptr, col, wgt, nullptr, nullptr, nullptr, slotC, nullptr);
  k_gemm<64, 256, 256, 8, true, false><<<1536, 256, 0, stream>>>(slotC, d1W2, d1b2, out_xs);

  // ---- dec1(z_s_cf)
  k_agg32<false><<<1536, 256, 0, stream>>>(slotE, rowptr, col, wgt, nullptr, slotD);       // gscf
  k_gemm<32, 64, 64, 8, true, true><<<384, 256, 0, stream>>>(slotD, d1W1, d1b1, slotB);    // u1cf
  k_agg64<false, false, false, false><<<3072, 256, 0, stream>>>(slotB, rowptr, col, wgt, nullptr, nullptr, nullptr, slotC, nullptr);
  k_gemm<64, 256, 256, 8, true, false><<<1536, 256, 0, stream>>>(slotC, d1W2, d1b2, out_xscf);

  // ---- gns = A(z_ns), shared by dec2 and s-conv
  k_agg32<false><<<1536, 256, 0, stream>>>(out_zns, rowptr, col, wgt, nullptr, slotE);

  // ---- hs = gns @ s_W + s_b, bf16 hi/lo (launch early: feeds the long pole)
  k_gemm_hs<<<384, 256, 0, stream>>>(slotE, sW, sb, hhi, hlo);

  // ---- dec2(z_ns)
  k_gemm<32, 64, 64, 8, true, true><<<384, 256, 0, stream>>>(slotE, d2W1, d2b1, slotB);    // u2
  k_agg64<false, false, false, false><<<3072, 256, 0, stream>>>(slotB, rowptr, col, wgt, nullptr, nullptr, nullptr, slotC, nullptr);
  k_gemm<64, 256, 256, 8, true, false><<<1536, 256, 0, stream>>>(slotC, d2W2, d2b2, out_xns);

  // ---- s_ = hs @ hs^T  (bf16 MFMA, hi/lo corrected)
  k_syrk_mfma<<<dim3(96, 96), 256, 0, stream>>>(hhi, hlo, out_s);
}